// Round 3
// baseline (185.118 us; speedup 1.0000x reference)
//
#include <hip/hip_runtime.h>
#include <math.h>

// Problem constants (B=64, J=17, H=W=128)
#define BJ    1088               // B*J map-pairs (pred_m paired with gt_m)
#define HW    16384              // 128*128
#define NTH   512                // 8 waves per block
#define NWAVE (NTH / 64)
#define F4PT  (HW / 4 / NTH)     // 8 float4 per thread per map

// Monotonic unsigned key for float bits: orders like float compare.
__device__ __forceinline__ unsigned int ford(unsigned int u) {
    return (u & 0x80000000u) ? ~u : (u | 0x80000000u);
}
__device__ __forceinline__ unsigned int ford_inv(unsigned int o) {
    return (o & 0x80000000u) ? (o & 0x7fffffffu) : ~o;
}

// R11: pair-fused single kernel, SEQUENTIAL phases (R10 post-mortem: holding
// both maps' 16 float4 under the 64-VGPR launch-bounds cap spilled to scratch
// -> 54 MB of WRITE_SIZE and a 2x regression). Only one map's 8 float4 is
// live at a time (32 VGPRs data, the R9 shape that compiled spill-free).
// Keeps R10's wins: single launch (no finalize kernel / d[] round-trip) and
// balanced grid (1088 blocks @ 4/CU = 1.06 residency waves vs 2.125 ragged).
// Per-phase reloads after the barrier hit L2/L3, not HBM (R9-proven).
__device__ __forceinline__ float map_stat(const float4* __restrict__ s4, int t,
                                          unsigned long long* rk,
                                          float* rs, float* rc)
{
    // ---- burst this map (8 float4 outstanding), 4-chain max scan
    float4 v[F4PT];
#pragma unroll
    for (int k = 0; k < F4PT; ++k) v[k] = s4[t + k * NTH];

    float mx0 = -INFINITY, mx1 = -INFINITY, mx2 = -INFINITY, mx3 = -INFINITY;
    int   ix0 = 0, ix1 = 1, ix2 = 2, ix3 = 3;
#pragma unroll
    for (int k = 0; k < F4PT; ++k) {               // idx grows with k -> '>' keeps first
        const int base = (t + k * NTH) << 2;
        if (v[k].x > mx0) { mx0 = v[k].x; ix0 = base;     }
        if (v[k].y > mx1) { mx1 = v[k].y; ix1 = base + 1; }
        if (v[k].z > mx2) { mx2 = v[k].z; ix2 = base + 2; }
        if (v[k].w > mx3) { mx3 = v[k].w; ix3 = base + 3; }
    }
    unsigned long long k0 = ((unsigned long long)ford(__float_as_uint(mx0)) << 32) | (unsigned int)~ix0;
    unsigned long long k1 = ((unsigned long long)ford(__float_as_uint(mx1)) << 32) | (unsigned int)~ix1;
    unsigned long long k2 = ((unsigned long long)ford(__float_as_uint(mx2)) << 32) | (unsigned int)~ix2;
    unsigned long long k3 = ((unsigned long long)ford(__float_as_uint(mx3)) << 32) | (unsigned int)~ix3;
    unsigned long long key = k0 > k1 ? k0 : k1;
    key = k2 > key ? k2 : key;
    key = k3 > key ? k3 : key;
#pragma unroll
    for (int off = 32; off >= 1; off >>= 1) {
        const unsigned long long ok = __shfl_xor(key, off, 64);
        key = (ok > key) ? ok : key;
    }
    const int wave = t >> 6, lane = t & 63;
    if (lane == 0) rk[wave] = key;
    __syncthreads();
    unsigned long long bkey = rk[0];
#pragma unroll
    for (int w = 1; w < NWAVE; ++w) bkey = (rk[w] > bkey) ? rk[w] : bkey;

    const float maxv = __uint_as_float(ford_inv((unsigned int)(bkey >> 32)));
    const int   midx = (int)~(unsigned int)(bkey & 0xffffffffu);
    const float ym  = (float)(midx >> 7);          // reference: idx // H (H=128 stride)
    const float xm  = (float)(midx & 127);
    const float thv = maxv * 0.5f;

    // ---- masked distance sum (v[] register-kept or cache-hit reloaded)
    float s = 0.0f, c = 0.0f;
#pragma unroll
    for (int k = 0; k < F4PT; ++k) {
        const float4 w = v[k];
        const int g4 = t + k * NTH;
        const float dy  = (float)(g4 >> 5) - ym;   // all 4 elems share a row
        const float dy2 = dy * dy;
        const float cb  = (float)((g4 << 2) & 127) - xm;
        {
            const float dx = cb;        const float ds = __builtin_amdgcn_sqrtf(fmaf(dx, dx, dy2));
            const float mk = (w.x > thv) ? 1.0f : 0.0f;  s = fmaf(mk, ds, s);  c += mk;
        }
        {
            const float dx = cb + 1.0f; const float ds = __builtin_amdgcn_sqrtf(fmaf(dx, dx, dy2));
            const float mk = (w.y > thv) ? 1.0f : 0.0f;  s = fmaf(mk, ds, s);  c += mk;
        }
        {
            const float dx = cb + 2.0f; const float ds = __builtin_amdgcn_sqrtf(fmaf(dx, dx, dy2));
            const float mk = (w.z > thv) ? 1.0f : 0.0f;  s = fmaf(mk, ds, s);  c += mk;
        }
        {
            const float dx = cb + 3.0f; const float ds = __builtin_amdgcn_sqrtf(fmaf(dx, dx, dy2));
            const float mk = (w.w > thv) ? 1.0f : 0.0f;  s = fmaf(mk, ds, s);  c += mk;
        }
    }

#pragma unroll
    for (int off = 32; off >= 1; off >>= 1) {
        s += __shfl_xor(s, off, 64);
        c += __shfl_xor(c, off, 64);
    }
    if (lane == 0) { rs[wave] = s; rc[wave] = c; }
    __syncthreads();                               // partials visible; also guards rk reuse
    float dd = 0.0f;
    if (t == 0) {
#pragma unroll
        for (int w = 1; w < NWAVE; ++w) { s += rs[w]; c += rc[w]; }
        const float mean = s / fmaxf(c, 1.0f);
        const float d0   = (c > 0.0f) ? (mean / 181.02f) : 1.0f;   // MAX_DIST
        dd = (maxv > 0.0f) ? d0 : 0.0f;
    }
    return dd;                                     // valid on t==0 only
}

__global__ __launch_bounds__(NTH, 8) void hm_pair(const float* __restrict__ outp,
                                                  const float* __restrict__ tgtp,
                                                  float* __restrict__ out)
{
    __shared__ unsigned long long rk[NWAVE];
    __shared__ float rs[NWAVE], rc[NWAVE];

    const int m = blockIdx.x;                      // [0, BJ)
    const int t = threadIdx.x;

    const float dP = map_stat((const float4*)(outp + (size_t)m * HW), t, rk, rs, rc);
    const float dG = map_stat((const float4*)(tgtp + (size_t)m * HW), t, rk, rs, rc);

    if (t == 0)
        atomicAdd(out, fabsf(dG - dP) * (1.0f / (17.0f * 64.0f)));
}

extern "C" void kernel_launch(void* const* d_in, const int* in_sizes, int n_in,
                              void* d_out, int out_size, void* d_ws, size_t ws_size,
                              hipStream_t stream) {
    const float* outp = (const float*)d_in[0];     // [64,17,128,128] f32
    const float* tgtp = (const float*)d_in[1];

    hipMemsetAsync(d_out, 0, sizeof(float), stream);
    hm_pair<<<dim3(BJ), dim3(NTH), 0, stream>>>(outp, tgtp, (float*)d_out);
}

// Round 4
// 177.159 us; speedup vs baseline: 1.0449x; 1.0449x over previous
//
#include <hip/hip_runtime.h>
#include <math.h>

// Problem constants (B=64, J=17, H=W=128)
#define BJ    1088               // B*J map-pairs (pred_m paired with gt_m)
#define HW    16384              // 128*128
#define NTH   512                // 8 waves per block
#define NWAVE (NTH / 64)
#define F4PT  (HW / 4 / NTH)     // 8 float4 per thread per map

// Monotonic unsigned key for float bits: orders like float compare.
__device__ __forceinline__ unsigned int ford(unsigned int u) {
    return (u & 0x80000000u) ? ~u : (u | 0x80000000u);
}
__device__ __forceinline__ unsigned int ford_inv(unsigned int o) {
    return (o & 0x80000000u) ? (o & 0x7fffffffu) : ~o;
}

// R12: pair-fused, sequential phases, EXPLICIT two-pass.
// R10/R11 post-mortem: any structure where v[8] (32 VGPRs of map data) is
// live across the max-barrier makes the compiler spill to scratch (54-59 MB
// WRITE_SIZE, 85-95 µs). R9 proved re-reads after the barrier are L2/L3
// hits (FETCH stayed at one-sweep). So: pass 1 loads v[], consumes it in
// the max-scan, and lets it DIE before the barrier; pass 2 re-reads the map
// through a LAUNDERED pointer (empty asm) so the compiler cannot CSE the
// reload with pass-1 values and recreate the spill-inducing live range.
// Keeps R10's wins: single launch, 1088 blocks @ 4/CU = 1.06 residency waves.
__device__ __forceinline__ float map_stat(const float* __restrict__ src, int t,
                                          unsigned long long* rk,
                                          float* rs, float* rc)
{
    const float4* __restrict__ s4 = (const float4*)src;

    // ---- pass 1: burst load (8 float4 outstanding), 4-chain max scan
    float4 v[F4PT];
#pragma unroll
    for (int k = 0; k < F4PT; ++k) v[k] = s4[t + k * NTH];

    float mx0 = -INFINITY, mx1 = -INFINITY, mx2 = -INFINITY, mx3 = -INFINITY;
    int   ix0 = 0, ix1 = 1, ix2 = 2, ix3 = 3;
#pragma unroll
    for (int k = 0; k < F4PT; ++k) {               // idx grows with k -> '>' keeps first
        const int base = (t + k * NTH) << 2;
        if (v[k].x > mx0) { mx0 = v[k].x; ix0 = base;     }
        if (v[k].y > mx1) { mx1 = v[k].y; ix1 = base + 1; }
        if (v[k].z > mx2) { mx2 = v[k].z; ix2 = base + 2; }
        if (v[k].w > mx3) { mx3 = v[k].w; ix3 = base + 3; }
    }
    // v[] is DEAD here — nothing large lives across the barrier.

    unsigned long long k0 = ((unsigned long long)ford(__float_as_uint(mx0)) << 32) | (unsigned int)~ix0;
    unsigned long long k1 = ((unsigned long long)ford(__float_as_uint(mx1)) << 32) | (unsigned int)~ix1;
    unsigned long long k2 = ((unsigned long long)ford(__float_as_uint(mx2)) << 32) | (unsigned int)~ix2;
    unsigned long long k3 = ((unsigned long long)ford(__float_as_uint(mx3)) << 32) | (unsigned int)~ix3;
    unsigned long long key = k0 > k1 ? k0 : k1;
    key = k2 > key ? k2 : key;
    key = k3 > key ? k3 : key;
#pragma unroll
    for (int off = 32; off >= 1; off >>= 1) {
        const unsigned long long ok = __shfl_xor(key, off, 64);
        key = (ok > key) ? ok : key;
    }
    const int wave = t >> 6, lane = t & 63;
    if (lane == 0) rk[wave] = key;
    __syncthreads();
    unsigned long long bkey = rk[0];
#pragma unroll
    for (int w = 1; w < NWAVE; ++w) bkey = (rk[w] > bkey) ? rk[w] : bkey;

    const float maxv = __uint_as_float(ford_inv((unsigned int)(bkey >> 32)));
    const int   midx = (int)~(unsigned int)(bkey & 0xffffffffu);
    const float ym  = (float)(midx >> 7);          // reference: idx // H (H=128 stride)
    const float xm  = (float)(midx & 127);
    const float thv = maxv * 0.5f;

    // ---- pass 2: explicit re-read through a laundered pointer.
    // The empty asm makes s4b opaque: loads below cannot be CSE'd with
    // pass-1 values, so they compile to real global loads (L2/L3 hits).
    const float4* s4b = (const float4*)src;
    asm volatile("" : "+v"(s4b));

    float s = 0.0f, c = 0.0f;
#pragma unroll
    for (int k = 0; k < F4PT; ++k) {
        const float4 w = s4b[t + k * NTH];
        const int g4 = t + k * NTH;
        const float dy  = (float)(g4 >> 5) - ym;   // all 4 elems share a row
        const float dy2 = dy * dy;
        const float cb  = (float)((g4 << 2) & 127) - xm;
        {
            const float dx = cb;        const float ds = __builtin_amdgcn_sqrtf(fmaf(dx, dx, dy2));
            const float mk = (w.x > thv) ? 1.0f : 0.0f;  s = fmaf(mk, ds, s);  c += mk;
        }
        {
            const float dx = cb + 1.0f; const float ds = __builtin_amdgcn_sqrtf(fmaf(dx, dx, dy2));
            const float mk = (w.y > thv) ? 1.0f : 0.0f;  s = fmaf(mk, ds, s);  c += mk;
        }
        {
            const float dx = cb + 2.0f; const float ds = __builtin_amdgcn_sqrtf(fmaf(dx, dx, dy2));
            const float mk = (w.z > thv) ? 1.0f : 0.0f;  s = fmaf(mk, ds, s);  c += mk;
        }
        {
            const float dx = cb + 3.0f; const float ds = __builtin_amdgcn_sqrtf(fmaf(dx, dx, dy2));
            const float mk = (w.w > thv) ? 1.0f : 0.0f;  s = fmaf(mk, ds, s);  c += mk;
        }
    }

#pragma unroll
    for (int off = 32; off >= 1; off >>= 1) {
        s += __shfl_xor(s, off, 64);
        c += __shfl_xor(c, off, 64);
    }
    if (lane == 0) { rs[wave] = s; rc[wave] = c; }
    __syncthreads();                               // partials visible; also guards rk reuse
    float dd = 0.0f;
    if (t == 0) {
#pragma unroll
        for (int w = 1; w < NWAVE; ++w) { s += rs[w]; c += rc[w]; }
        const float mean = s / fmaxf(c, 1.0f);
        const float d0   = (c > 0.0f) ? (mean / 181.02f) : 1.0f;   // MAX_DIST
        dd = (maxv > 0.0f) ? d0 : 0.0f;
    }
    return dd;                                     // valid on t==0 only
}

__global__ __launch_bounds__(NTH, 8) void hm_pair(const float* __restrict__ outp,
                                                  const float* __restrict__ tgtp,
                                                  float* __restrict__ out)
{
    __shared__ unsigned long long rk[NWAVE];
    __shared__ float rs[NWAVE], rc[NWAVE];

    const int m = blockIdx.x;                      // [0, BJ)
    const int t = threadIdx.x;

    const float dP = map_stat(outp + (size_t)m * HW, t, rk, rs, rc);
    const float dG = map_stat(tgtp + (size_t)m * HW, t, rk, rs, rc);

    if (t == 0)
        atomicAdd(out, fabsf(dG - dP) * (1.0f / (17.0f * 64.0f)));
}

extern "C" void kernel_launch(void* const* d_in, const int* in_sizes, int n_in,
                              void* d_out, int out_size, void* d_ws, size_t ws_size,
                              hipStream_t stream) {
    const float* outp = (const float*)d_in[0];     // [64,17,128,128] f32
    const float* tgtp = (const float*)d_in[1];

    hipMemsetAsync(d_out, 0, sizeof(float), stream);
    hm_pair<<<dim3(BJ), dim3(NTH), 0, stream>>>(outp, tgtp, (float*)d_out);
}

// Round 5
// 163.247 us; speedup vs baseline: 1.1340x; 1.0852x over previous
//
#include <hip/hip_runtime.h>
#include <math.h>

// Problem constants (B=64, J=17, H=W=128)
#define BJ    1088               // B*J map-pairs (pred_m paired with gt_m)
#define HW    16384              // 128*128
#define NTH   512                // 8 waves per block
#define NWAVE (NTH / 64)
#define F4PT  (HW / 4 / NTH)     // 8 float4 per thread per map

// Monotonic unsigned key for float bits: orders like float compare.
__device__ __forceinline__ unsigned int ford(unsigned int u) {
    return (u & 0x80000000u) ? ~u : (u | 0x80000000u);
}
__device__ __forceinline__ unsigned int ford_inv(unsigned int o) {
    return (o & 0x80000000u) ? (o & 0x7fffffffu) : ~o;
}

// R13 = R7's proven LDS-staged body (52.6 µs, one HBM sweep, zero spill)
// + R10's proven launch fusion (one kernel, no finalize, no d[] round-trip).
// R12 post-mortem: explicit re-read doubled HBM demand (FETCH 70->147 MB,
// 71 µs) — "reloads hit L3" was wrong at this concurrency. R10/R11: keeping
// v[] live across the barrier spills (54-59 MB scratch writes). The ONLY
// verified one-sweep-zero-spill structure is LDS staging; v[] dies before
// the barrier, masked sum re-reads each thread's OWN staged LDS slots.
// LDS reuse across the two maps is hazard-free: hm4[t+k*NTH] slots are
// read/written by the same thread only (program order), and rk/rs/rc reuse
// is ordered by the two existing barriers per map.
__device__ __forceinline__ float map_stat(const float* __restrict__ src, int t,
                                          float* hm,
                                          unsigned long long* rk,
                                          float* rs, float* rc)
{
    const float4* __restrict__ s4 = (const float4*)src;
    float4* hm4 = (float4*)hm;

    // ---- single load burst (8 float4 outstanding), stage to LDS + 4-chain scan
    float4 v[F4PT];
#pragma unroll
    for (int k = 0; k < F4PT; ++k) v[k] = s4[t + k * NTH];

    float mx0 = -INFINITY, mx1 = -INFINITY, mx2 = -INFINITY, mx3 = -INFINITY;
    int   ix0 = 0, ix1 = 1, ix2 = 2, ix3 = 3;
#pragma unroll
    for (int k = 0; k < F4PT; ++k) {               // idx grows with k -> '>' keeps first
        hm4[t + k * NTH] = v[k];
        const int base = (t + k * NTH) << 2;
        if (v[k].x > mx0) { mx0 = v[k].x; ix0 = base;     }
        if (v[k].y > mx1) { mx1 = v[k].y; ix1 = base + 1; }
        if (v[k].z > mx2) { mx2 = v[k].z; ix2 = base + 2; }
        if (v[k].w > mx3) { mx3 = v[k].w; ix3 = base + 3; }
    }
    // v[] dead here — nothing large lives across the barrier.

    unsigned long long k0 = ((unsigned long long)ford(__float_as_uint(mx0)) << 32) | (unsigned int)~ix0;
    unsigned long long k1 = ((unsigned long long)ford(__float_as_uint(mx1)) << 32) | (unsigned int)~ix1;
    unsigned long long k2 = ((unsigned long long)ford(__float_as_uint(mx2)) << 32) | (unsigned int)~ix2;
    unsigned long long k3 = ((unsigned long long)ford(__float_as_uint(mx3)) << 32) | (unsigned int)~ix3;
    unsigned long long key = k0 > k1 ? k0 : k1;
    key = k2 > key ? k2 : key;
    key = k3 > key ? k3 : key;
#pragma unroll
    for (int off = 32; off >= 1; off >>= 1) {
        const unsigned long long ok = __shfl_xor(key, off, 64);
        key = (ok > key) ? ok : key;
    }
    const int wave = t >> 6, lane = t & 63;
    if (lane == 0) rk[wave] = key;
    __syncthreads();                               // barrier A: rk visible
    unsigned long long bkey = rk[0];
#pragma unroll
    for (int w = 1; w < NWAVE; ++w) bkey = (rk[w] > bkey) ? rk[w] : bkey;

    const float maxv = __uint_as_float(ford_inv((unsigned int)(bkey >> 32)));
    const int   midx = (int)~(unsigned int)(bkey & 0xffffffffu);
    const float ym  = (float)(midx >> 7);          // reference: idx // H (H=128 stride)
    const float xm  = (float)(midx & 127);
    const float thv = maxv * 0.5f;

    // ---- masked distance sum from own staged LDS slots (no barrier needed)
    float s = 0.0f, c = 0.0f;
#pragma unroll
    for (int k = 0; k < F4PT; ++k) {
        const float4 w = hm4[t + k * NTH];
        const int g4 = t + k * NTH;
        const float dy  = (float)(g4 >> 5) - ym;   // all 4 elems share a row
        const float dy2 = dy * dy;
        const float cb  = (float)((g4 << 2) & 127) - xm;
        {
            const float dx = cb;        const float ds = __builtin_amdgcn_sqrtf(fmaf(dx, dx, dy2));
            const float mk = (w.x > thv) ? 1.0f : 0.0f;  s = fmaf(mk, ds, s);  c += mk;
        }
        {
            const float dx = cb + 1.0f; const float ds = __builtin_amdgcn_sqrtf(fmaf(dx, dx, dy2));
            const float mk = (w.y > thv) ? 1.0f : 0.0f;  s = fmaf(mk, ds, s);  c += mk;
        }
        {
            const float dx = cb + 2.0f; const float ds = __builtin_amdgcn_sqrtf(fmaf(dx, dx, dy2));
            const float mk = (w.z > thv) ? 1.0f : 0.0f;  s = fmaf(mk, ds, s);  c += mk;
        }
        {
            const float dx = cb + 3.0f; const float ds = __builtin_amdgcn_sqrtf(fmaf(dx, dx, dy2));
            const float mk = (w.w > thv) ? 1.0f : 0.0f;  s = fmaf(mk, ds, s);  c += mk;
        }
    }

#pragma unroll
    for (int off = 32; off >= 1; off >>= 1) {
        s += __shfl_xor(s, off, 64);
        c += __shfl_xor(c, off, 64);
    }
    if (lane == 0) { rs[wave] = s; rc[wave] = c; }
    __syncthreads();                               // barrier B: rs/rc visible, rk/hm free
    float dd = 0.0f;
    if (t == 0) {
#pragma unroll
        for (int w = 1; w < NWAVE; ++w) { s += rs[w]; c += rc[w]; }
        const float mean = s / fmaxf(c, 1.0f);
        const float d0   = (c > 0.0f) ? (mean / 181.02f) : 1.0f;   // MAX_DIST
        dd = (maxv > 0.0f) ? d0 : 0.0f;
    }
    return dd;                                     // valid on t==0 only
}

__global__ __launch_bounds__(NTH, 4) void hm_pair(const float* __restrict__ outp,
                                                  const float* __restrict__ tgtp,
                                                  float* __restrict__ out)
{
    __shared__ float hm[HW];                       // 64 KB, reused by both maps
    __shared__ unsigned long long rk[NWAVE];
    __shared__ float rs[NWAVE], rc[NWAVE];

    const int m = blockIdx.x;                      // [0, BJ)
    const int t = threadIdx.x;

    const float dP = map_stat(outp + (size_t)m * HW, t, hm, rk, rs, rc);
    const float dG = map_stat(tgtp + (size_t)m * HW, t, hm, rk, rs, rc);

    if (t == 0)
        atomicAdd(out, fabsf(dG - dP) * (1.0f / (17.0f * 64.0f)));
}

extern "C" void kernel_launch(void* const* d_in, const int* in_sizes, int n_in,
                              void* d_out, int out_size, void* d_ws, size_t ws_size,
                              hipStream_t stream) {
    const float* outp = (const float*)d_in[0];     // [64,17,128,128] f32
    const float* tgtp = (const float*)d_in[1];

    hipMemsetAsync(d_out, 0, sizeof(float), stream);
    hm_pair<<<dim3(BJ), dim3(NTH), 0, stream>>>(outp, tgtp, (float*)d_out);
}